// Round 8
// baseline (227.781 us; speedup 1.0000x reference)
//
#include <hip/hip_runtime.h>
#include <hip/hip_bf16.h>
#include <cstdint>

typedef __bf16 bf16x4 __attribute__((ext_vector_type(4)));
typedef float  f32x4  __attribute__((ext_vector_type(4)));
typedef int    i32x4  __attribute__((ext_vector_type(4)));
typedef int    i32x8  __attribute__((ext_vector_type(8)));

#define B_ROWS 4096
#define IN_DIM 1024
#define HIDDEN 8192
#define KEEP   256

using gptr_t = const __attribute__((address_space(1))) void*;
using lptr_t = __attribute__((address_space(3))) void*;

__device__ __forceinline__ void async_load16(const void* g, void* l) {
    gptr_t gp = reinterpret_cast<gptr_t>(reinterpret_cast<uintptr_t>(g));
    lptr_t lp = reinterpret_cast<lptr_t>(reinterpret_cast<uintptr_t>(l));
    __builtin_amdgcn_global_load_lds(gp, lp, 16, 0, 0);
}

__device__ __forceinline__ unsigned char f32_to_fp8(float v) {
    return (unsigned char)(__builtin_amdgcn_cvt_pk_fp8_f32(v, v, 0, false) & 0xFF);
}

// ---------------------------------------------------------------------------
// C[M,N] = A[M,K] @ B[N,K]^T, fp8 e4m3, MX MFMA (unit scales), fp32 accum.
// EPI==0: store fp8 C (encode).  EPI==1: store bf16 C partial z (decode).
// BKB bytes per K-tile row = BKB/16 slots of 16B; XOR-swizzle (low 3 row
// bits) applied on the GLOBAL side so global_load_lds's lane-order LDS write
// stays natural. BKB=256 for decode halves barrier-drain count (r7 showed
// occupancy 3 vs 4 blk/CU is neutral -> drains are the binding term).
// ---------------------------------------------------------------------------
template<int BM, int BN, int WROWS, int WCOLS, int EPI, int BKB, int MINW>
__global__ __launch_bounds__(256, MINW)
void gemm_nt_fp8(const unsigned char* __restrict__ A, int lda,
                 const unsigned char* __restrict__ Bm, int ldb,
                 void* __restrict__ Cout, int M, int N, int Kloop)
{
    constexpr int WTM   = BM / WROWS / 16;
    constexpr int WTN   = BN / WCOLS / 16;
    constexpr int SLOTS = BKB / 16;          // 16B slots per row
    constexpr int RPC   = 1024 / BKB;        // rows covered per DMA call
    constexpr int KS    = BKB / 128;         // MFMA k-steps per K-tile

    __shared__ __align__(16) unsigned char As[BM * BKB];
    __shared__ __align__(16) unsigned char Bs[BN * BKB];

    const int tid  = threadIdx.x;
    const int wave = tid >> 6;
    const int lane = tid & 63;
    const long long block_m = (long long)blockIdx.y * BM;
    const long long block_n = (long long)blockIdx.x * BN;

    A  += (long long)blockIdx.z * Kloop;
    Bm += (long long)blockIdx.z * Kloop;

    const int wm = (wave / WCOLS) * (WTM * 16);
    const int wn = (wave % WCOLS) * (WTN * 16);

    f32x4 acc[WTM][WTN] = {};

    constexpr int A_CALLS = BM * BKB / 4096;  // per wave
    constexpr int B_CALLS = BN * BKB / 4096;
    const int sub_row = lane / SLOTS;                 // 0..RPC-1
    const int slot    = lane & (SLOTS - 1);
    const int lds_off = lane * 16;                    // natural LDS byte off

    const int lm = lane & 15;
    const int lq = lane >> 4;

    for (int kt = 0; kt < Kloop; kt += BKB) {
        #pragma unroll
        for (int c = 0; c < A_CALLS; ++c) {
            const int row  = (wave * A_CALLS + c) * RPC + sub_row;
            const int kg   = (slot ^ (row & 7)) * 16;
            async_load16(A + (block_m + row) * (long long)lda + kt + kg,
                         &As[(wave * A_CALLS + c) * 1024 + lds_off]);
        }
        #pragma unroll
        for (int c = 0; c < B_CALLS; ++c) {
            const int row  = (wave * B_CALLS + c) * RPC + sub_row;
            const int kg   = (slot ^ (row & 7)) * 16;
            async_load16(Bm + (block_n + row) * (long long)ldb + kt + kg,
                         &Bs[(wave * B_CALLS + c) * 1024 + lds_off]);
        }
        __syncthreads();

        #pragma unroll
        for (int ks = 0; ks < KS; ++ks) {
            i32x8 af[WTM], bfq[WTN];
            #pragma unroll
            for (int i = 0; i < WTM; ++i) {
                const int r = wm + i * 16 + lm;
                const int s0 = ks * 8 + (((2 * lq) ^ (r & 7)) & 7);
                const int s1 = ks * 8 + (((2 * lq + 1) ^ (r & 7)) & 7);
                const i32x4 lo = *(const i32x4*)&As[r * BKB + s0 * 16];
                const i32x4 hi = *(const i32x4*)&As[r * BKB + s1 * 16];
                af[i] = i32x8{lo.x, lo.y, lo.z, lo.w, hi.x, hi.y, hi.z, hi.w};
            }
            #pragma unroll
            for (int j = 0; j < WTN; ++j) {
                const int r = wn + j * 16 + lm;
                const int s0 = ks * 8 + (((2 * lq) ^ (r & 7)) & 7);
                const int s1 = ks * 8 + (((2 * lq + 1) ^ (r & 7)) & 7);
                const i32x4 lo = *(const i32x4*)&Bs[r * BKB + s0 * 16];
                const i32x4 hi = *(const i32x4*)&Bs[r * BKB + s1 * 16];
                bfq[j] = i32x8{lo.x, lo.y, lo.z, lo.w, hi.x, hi.y, hi.z, hi.w};
            }
            #pragma unroll
            for (int i = 0; i < WTM; ++i)
                #pragma unroll
                for (int j = 0; j < WTN; ++j)
                    acc[i][j] = __builtin_amdgcn_mfma_scale_f32_16x16x128_f8f6f4(
                        af[i], bfq[j], acc[i][j],
                        0, 0, 0, 0x7F7F7F7F, 0, 0x7F7F7F7F);
        }
        __syncthreads();
    }

    // D[m][n]: n = lane&15, m = 4*(lane>>4)+r
    const int rbase = lq * 4;
    if constexpr (EPI == 0) {
        unsigned char* Hh = (unsigned char*)Cout;
        #pragma unroll
        for (int i = 0; i < WTM; ++i)
            #pragma unroll
            for (int j = 0; j < WTN; ++j)
                #pragma unroll
                for (int r = 0; r < 4; ++r) {
                    const long long m = block_m + wm + i * 16 + rbase + r;
                    const long long n = block_n + wn + j * 16 + lm;
                    Hh[m * N + n] = f32_to_fp8(acc[i][j][r]);
                }
    } else {
        __bf16* Cp = (__bf16*)Cout + (size_t)blockIdx.z * (size_t)M * N;
        #pragma unroll
        for (int i = 0; i < WTM; ++i)
            #pragma unroll
            for (int j = 0; j < WTN; ++j)
                #pragma unroll
                for (int r = 0; r < 4; ++r) {
                    const long long m = block_m + wm + i * 16 + rbase + r;
                    const long long n = block_n + wn + j * 16 + lm;
                    Cp[m * N + n] = (__bf16)acc[i][j][r];
                }
    }
}

// ---------------------------------------------------------------------------
// out = x + gate * (P0 + P1)   (bf16 partials -> fp32 out)
// ---------------------------------------------------------------------------
__global__ __launch_bounds__(256)
void reduce_out(const __bf16* __restrict__ P, const float* __restrict__ x,
                const float* __restrict__ gate, float* __restrict__ out)
{
    const int i = blockIdx.x * 256 + threadIdx.x;
    const float4 xv = ((const float4*)x)[i];
    const bf16x4 p0 = ((const bf16x4*)P)[i];
    const bf16x4 p1 = ((const bf16x4*)(P + (size_t)B_ROWS * IN_DIM))[i];
    const float4 g  = ((const float4*)gate)[i & (IN_DIM / 4 - 1)];
    float4 o;
    o.x = xv.x + g.x * ((float)p0.x + (float)p1.x);
    o.y = xv.y + g.y * ((float)p0.y + (float)p1.y);
    o.z = xv.z + g.z * ((float)p0.z + (float)p1.z);
    o.w = xv.w + g.w * ((float)p0.w + (float)p1.w);
    ((float4*)out)[i] = o;
}

// ---------------------------------------------------------------------------
// One dispatch: cast Wenc+Wdec fp32->fp8 (blocks 0..16383) and
// row-normalize x -> fp8 (blocks 16384..20479).
// ---------------------------------------------------------------------------
__global__ __launch_bounds__(256)
void prep(const float* __restrict__ Wenc, const float* __restrict__ Wdec,
          const float* __restrict__ x,
          unsigned char* __restrict__ WencB, unsigned char* __restrict__ WdecB,
          unsigned char* __restrict__ xn)
{
    constexpr int N4 = HIDDEN * IN_DIM / 4;
    constexpr int WBLK = 2 * N4 / 256;
    const int t = threadIdx.x;

    if (blockIdx.x < WBLK) {
        int i = blockIdx.x * 256 + t;
        const float* src; unsigned char* dst;
        if (i < N4) { src = Wenc; dst = WencB; }
        else        { src = Wdec; dst = WdecB; i -= N4; }
        const float4 v = ((const float4*)src)[i];
        int p = __builtin_amdgcn_cvt_pk_fp8_f32(v.x, v.y, 0, false);
        p     = __builtin_amdgcn_cvt_pk_fp8_f32(v.z, v.w, p, true);
        ((int*)dst)[i] = p;
    } else {
        const int row = blockIdx.x - WBLK;
        const float4 v = ((const float4*)(x + (long long)row * IN_DIM))[t];
        float ss = v.x * v.x + v.y * v.y + v.z * v.z + v.w * v.w;
        #pragma unroll
        for (int off = 32; off > 0; off >>= 1) ss += __shfl_down(ss, off);
        __shared__ float part[4];
        if ((t & 63) == 0) part[t >> 6] = ss;
        __syncthreads();
        const float tot = part[0] + part[1] + part[2] + part[3];
        const float inv = 1.0f / fmaxf(sqrtf(tot), 1e-12f);
        int p = __builtin_amdgcn_cvt_pk_fp8_f32(v.x * inv, v.y * inv, 0, false);
        p     = __builtin_amdgcn_cvt_pk_fp8_f32(v.z * inv, v.w * inv, p, true);
        ((int*)(xn + (long long)row * IN_DIM))[t] = p;
    }
}

// ---------------------------------------------------------------------------
// Per-row top-K mask in place on fp8 hidden.
// 8-copy bank-spread LDS histogram, wave-0 shuffle suffix-scan, mask from
// registers. Keeps all values >= T (tie surplus contributes ~1e-4 << 0.1).
// ---------------------------------------------------------------------------
__global__ __launch_bounds__(256)
void topk_mask8(unsigned int* __restrict__ H)
{
    __shared__ unsigned int hist8[256 * 8];
    __shared__ unsigned int sT;
    const int t = threadIdx.x;
    unsigned int* row = H + (size_t)blockIdx.x * (HIDDEN / 4);

    #pragma unroll
    for (int i = 0; i < 8; ++i) hist8[i * 256 + t] = 0;
    __syncthreads();

    unsigned int rw[8];
    const int cp = t & 7;
    #pragma unroll
    for (int i = 0; i < 8; ++i) {
        rw[i] = row[i * 256 + t];
        #pragma unroll
        for (int e = 0; e < 4; ++e) {
            const unsigned int b = (rw[i] >> (8 * e)) & 0xFFu;
            const unsigned int k = b ^ ((b & 0x80u) ? 0xFFu : 0x80u);
            atomicAdd(&hist8[k * 8 + cp], 1u);
        }
    }
    __syncthreads();

    unsigned int cnt = 0;
    #pragma unroll
    for (int c = 0; c < 8; ++c) cnt += hist8[t * 8 + c];
    __syncthreads();
    hist8[t] = cnt;
    __syncthreads();

    if (t < 64) {
        const uint4 c4 = *(const uint4*)&hist8[4 * t];
        const unsigned s3 = c4.w;
        const unsigned s2 = c4.z + s3;
        const unsigned s1 = c4.y + s2;
        const unsigned s0 = c4.x + s1;
        unsigned inc = s0;
        #pragma unroll
        for (int off = 1; off < 64; off <<= 1) {
            unsigned o = __shfl_down(inc, off);
            if (t + off >= 64) o = 0;
            inc += o;
        }
        const unsigned carry = inc - s0;
        const unsigned a0 = s0 + carry, a1 = s1 + carry;
        const unsigned a2 = s2 + carry, a3 = s3 + carry;
        if (a0 >= KEEP && a1 < KEEP)    sT = 4u * t + 0u;
        if (a1 >= KEEP && a2 < KEEP)    sT = 4u * t + 1u;
        if (a2 >= KEEP && a3 < KEEP)    sT = 4u * t + 2u;
        if (a3 >= KEEP && carry < KEEP) sT = 4u * t + 3u;
    }
    __syncthreads();
    const unsigned int T = sT;

    #pragma unroll
    for (int i = 0; i < 8; ++i) {
        const unsigned int kw = rw[i];
        unsigned int ow = 0;
        #pragma unroll
        for (int e = 0; e < 4; ++e) {
            const unsigned int b = (kw >> (8 * e)) & 0xFFu;
            const unsigned int k = b ^ ((b & 0x80u) ? 0xFFu : 0x80u);
            if (k >= T) ow |= b << (8 * e);
        }
        row[i * 256 + t] = ow;
    }
}

// ---------------------------------------------------------------------------
extern "C" void kernel_launch(void* const* d_in, const int* in_sizes, int n_in,
                              void* d_out, int out_size, void* d_ws, size_t ws_size,
                              hipStream_t stream)
{
    const float* x    = (const float*)d_in[0];   // [4096,1024]
    const float* Wenc = (const float*)d_in[1];   // [8192,1024]
    const float* Wdec = (const float*)d_in[2];   // [1024,8192]
    const float* gate = (const float*)d_in[3];   // [1024]
    float* out = (float*)d_out;

    char* ws = (char*)d_ws;
    unsigned char* xn    = (unsigned char*)(ws);                        //  4 MB
    unsigned char* WencB = (unsigned char*)(ws + (size_t)( 4 << 20));   //  8 MB
    unsigned char* WdecB = (unsigned char*)(ws + (size_t)(12 << 20));   //  8 MB
    unsigned char* Hbuf  = (unsigned char*)(ws + (size_t)(20 << 20));   // 32 MB
    __bf16*        Part  = (__bf16*)       (ws + (size_t)(52 << 20));   // 16 MB

    constexpr int N4 = HIDDEN * IN_DIM / 4;
    prep<<<2 * N4 / 256 + B_ROWS, 256, 0, stream>>>(Wenc, Wdec, x, WencB, WdecB, xn);

    // hidden[4096,8192] = xn @ Wenc^T  (fp8 out, BK=128 unchanged)
    gemm_nt_fp8<128, 128, 2, 2, 0, 128, 4>
        <<<dim3(HIDDEN / 128, B_ROWS / 128, 1), 256, 0, stream>>>(
        xn, IN_DIM, WencB, IN_DIM, (void*)Hbuf, B_ROWS, HIDDEN, IN_DIM);

    topk_mask8<<<B_ROWS, 256, 0, stream>>>((unsigned int*)Hbuf);

    // partials[z][4096,1024] = act_z @ Wdec_z^T  (bf16 out, split-K=2, BK=256)
    gemm_nt_fp8<128, 64, 2, 2, 1, 256, 3>
        <<<dim3(IN_DIM / 64, B_ROWS / 128, 2), 256, 0, stream>>>(
        Hbuf, HIDDEN, WdecB, HIDDEN, (void*)Part, B_ROWS, IN_DIM, HIDDEN / 2);

    reduce_out<<<B_ROWS * IN_DIM / 4 / 256, 256, 0, stream>>>(Part, x, gate, out);
}

// Round 9
// 219.310 us; speedup vs baseline: 1.0386x; 1.0386x over previous
//
#include <hip/hip_runtime.h>
#include <hip/hip_bf16.h>
#include <cstdint>

typedef __bf16 bf16x4 __attribute__((ext_vector_type(4)));
typedef float  f32x4  __attribute__((ext_vector_type(4)));
typedef int    i32x4  __attribute__((ext_vector_type(4)));
typedef int    i32x8  __attribute__((ext_vector_type(8)));

#define B_ROWS 4096
#define IN_DIM 1024
#define HIDDEN 8192
#define KEEP   256

using gptr_t = const __attribute__((address_space(1))) void*;
using lptr_t = __attribute__((address_space(3))) void*;

__device__ __forceinline__ void async_load16(const void* g, void* l) {
    gptr_t gp = reinterpret_cast<gptr_t>(reinterpret_cast<uintptr_t>(g));
    lptr_t lp = reinterpret_cast<lptr_t>(reinterpret_cast<uintptr_t>(l));
    __builtin_amdgcn_global_load_lds(gp, lp, 16, 0, 0);
}

__device__ __forceinline__ unsigned char f32_to_fp8(float v) {
    return (unsigned char)(__builtin_amdgcn_cvt_pk_fp8_f32(v, v, 0, false) & 0xFF);
}

// ---------------------------------------------------------------------------
// C[M,N] = A[M,K] @ B[N,K]^T, fp8 e4m3, MX MFMA (unit scales), fp32 accum.
// EPI==0: store fp8 C (encode).  EPI==1: store bf16 C partial z (decode).
// BKB=128 B rows = 8x16B slots, XOR-swizzled on the global side so
// global_load_lds's lane-order LDS write stays natural.
// CONFIG NOTES (measured):
//  - r5: atomic split-K epilogue  -> decode 81us (L2 RMW serialization). NO.
//  - r7: launch_bounds(256,4)     -> neutral (barrier drain binds, not occ).
//  - r8: BKB=256                  -> 59us (VGPR 76+64A -> ~2 blk/CU). NO.
//  - r6 config below = best: decode 48.2us, encode 48.4us, total 220us.
// ---------------------------------------------------------------------------
template<int BM, int BN, int WROWS, int WCOLS, int EPI>
__global__ __launch_bounds__(256, 3)
void gemm_nt_fp8(const unsigned char* __restrict__ A, int lda,
                 const unsigned char* __restrict__ Bm, int ldb,
                 void* __restrict__ Cout, int M, int N, int Kloop)
{
    constexpr int BKB = 128;
    constexpr int WTM = BM / WROWS / 16;
    constexpr int WTN = BN / WCOLS / 16;

    __shared__ __align__(16) unsigned char As[BM * BKB];
    __shared__ __align__(16) unsigned char Bs[BN * BKB];

    const int tid  = threadIdx.x;
    const int wave = tid >> 6;
    const int lane = tid & 63;
    const long long block_m = (long long)blockIdx.y * BM;
    const long long block_n = (long long)blockIdx.x * BN;

    A  += (long long)blockIdx.z * Kloop;
    Bm += (long long)blockIdx.z * Kloop;

    const int wm = (wave / WCOLS) * (WTM * 16);
    const int wn = (wave % WCOLS) * (WTN * 16);

    f32x4 acc[WTM][WTN] = {};

    constexpr int A_CALLS = BM / 32;
    constexpr int B_CALLS = BN / 32;
    const int sub_row = lane >> 3;
    const int slot    = lane & 7;
    const int kg_sw   = (slot ^ sub_row) * 16;
    const int koff_n  = slot * 16;

    const int lm = lane & 15;
    const int lq = lane >> 4;

    for (int kt = 0; kt < Kloop; kt += BKB) {
        #pragma unroll
        for (int c = 0; c < A_CALLS; ++c) {
            const int row = (wave * A_CALLS + c) * 8 + sub_row;
            async_load16(A + (block_m + row) * (long long)lda + kt + kg_sw,
                         &As[row * BKB + koff_n]);
        }
        #pragma unroll
        for (int c = 0; c < B_CALLS; ++c) {
            const int row = (wave * B_CALLS + c) * 8 + sub_row;
            async_load16(Bm + (block_n + row) * (long long)ldb + kt + kg_sw,
                         &Bs[row * BKB + koff_n]);
        }
        __syncthreads();

        i32x8 af[WTM], bfq[WTN];
        #pragma unroll
        for (int i = 0; i < WTM; ++i) {
            const int r = wm + i * 16 + lm;
            const i32x4 lo = *(const i32x4*)&As[r * BKB + (((2 * lq) ^ (r & 7)) * 16)];
            const i32x4 hi = *(const i32x4*)&As[r * BKB + (((2 * lq + 1) ^ (r & 7)) * 16)];
            af[i] = i32x8{lo.x, lo.y, lo.z, lo.w, hi.x, hi.y, hi.z, hi.w};
        }
        #pragma unroll
        for (int j = 0; j < WTN; ++j) {
            const int r = wn + j * 16 + lm;
            const i32x4 lo = *(const i32x4*)&Bs[r * BKB + (((2 * lq) ^ (r & 7)) * 16)];
            const i32x4 hi = *(const i32x4*)&Bs[r * BKB + (((2 * lq + 1) ^ (r & 7)) * 16)];
            bfq[j] = i32x8{lo.x, lo.y, lo.z, lo.w, hi.x, hi.y, hi.z, hi.w};
        }
        #pragma unroll
        for (int i = 0; i < WTM; ++i)
            #pragma unroll
            for (int j = 0; j < WTN; ++j)
                acc[i][j] = __builtin_amdgcn_mfma_scale_f32_16x16x128_f8f6f4(
                    af[i], bfq[j], acc[i][j],
                    0, 0, 0, 0x7F7F7F7F, 0, 0x7F7F7F7F);
        __syncthreads();
    }

    // D[m][n]: n = lane&15, m = 4*(lane>>4)+r
    const int rbase = lq * 4;
    if constexpr (EPI == 0) {
        unsigned char* Hh = (unsigned char*)Cout;
        #pragma unroll
        for (int i = 0; i < WTM; ++i)
            #pragma unroll
            for (int j = 0; j < WTN; ++j)
                #pragma unroll
                for (int r = 0; r < 4; ++r) {
                    const long long m = block_m + wm + i * 16 + rbase + r;
                    const long long n = block_n + wn + j * 16 + lm;
                    Hh[m * N + n] = f32_to_fp8(acc[i][j][r]);
                }
    } else {
        __bf16* Cp = (__bf16*)Cout + (size_t)blockIdx.z * (size_t)M * N;
        #pragma unroll
        for (int i = 0; i < WTM; ++i)
            #pragma unroll
            for (int j = 0; j < WTN; ++j)
                #pragma unroll
                for (int r = 0; r < 4; ++r) {
                    const long long m = block_m + wm + i * 16 + rbase + r;
                    const long long n = block_n + wn + j * 16 + lm;
                    Cp[m * N + n] = (__bf16)acc[i][j][r];
                }
    }
}

// ---------------------------------------------------------------------------
// out = x + gate * (P0 + P1)   (bf16 partials -> fp32 out)
// ---------------------------------------------------------------------------
__global__ __launch_bounds__(256)
void reduce_out(const __bf16* __restrict__ P, const float* __restrict__ x,
                const float* __restrict__ gate, float* __restrict__ out)
{
    const int i = blockIdx.x * 256 + threadIdx.x;
    const float4 xv = ((const float4*)x)[i];
    const bf16x4 p0 = ((const bf16x4*)P)[i];
    const bf16x4 p1 = ((const bf16x4*)(P + (size_t)B_ROWS * IN_DIM))[i];
    const float4 g  = ((const float4*)gate)[i & (IN_DIM / 4 - 1)];
    float4 o;
    o.x = xv.x + g.x * ((float)p0.x + (float)p1.x);
    o.y = xv.y + g.y * ((float)p0.y + (float)p1.y);
    o.z = xv.z + g.z * ((float)p0.z + (float)p1.z);
    o.w = xv.w + g.w * ((float)p0.w + (float)p1.w);
    ((float4*)out)[i] = o;
}

// ---------------------------------------------------------------------------
// One dispatch: cast Wenc+Wdec fp32->fp8 (blocks 0..16383) and
// row-normalize x -> fp8 (blocks 16384..20479).
// ---------------------------------------------------------------------------
__global__ __launch_bounds__(256)
void prep(const float* __restrict__ Wenc, const float* __restrict__ Wdec,
          const float* __restrict__ x,
          unsigned char* __restrict__ WencB, unsigned char* __restrict__ WdecB,
          unsigned char* __restrict__ xn)
{
    constexpr int N4 = HIDDEN * IN_DIM / 4;
    constexpr int WBLK = 2 * N4 / 256;
    const int t = threadIdx.x;

    if (blockIdx.x < WBLK) {
        int i = blockIdx.x * 256 + t;
        const float* src; unsigned char* dst;
        if (i < N4) { src = Wenc; dst = WencB; }
        else        { src = Wdec; dst = WdecB; i -= N4; }
        const float4 v = ((const float4*)src)[i];
        int p = __builtin_amdgcn_cvt_pk_fp8_f32(v.x, v.y, 0, false);
        p     = __builtin_amdgcn_cvt_pk_fp8_f32(v.z, v.w, p, true);
        ((int*)dst)[i] = p;
    } else {
        const int row = blockIdx.x - WBLK;
        const float4 v = ((const float4*)(x + (long long)row * IN_DIM))[t];
        float ss = v.x * v.x + v.y * v.y + v.z * v.z + v.w * v.w;
        #pragma unroll
        for (int off = 32; off > 0; off >>= 1) ss += __shfl_down(ss, off);
        __shared__ float part[4];
        if ((t & 63) == 0) part[t >> 6] = ss;
        __syncthreads();
        const float tot = part[0] + part[1] + part[2] + part[3];
        const float inv = 1.0f / fmaxf(sqrtf(tot), 1e-12f);
        int p = __builtin_amdgcn_cvt_pk_fp8_f32(v.x * inv, v.y * inv, 0, false);
        p     = __builtin_amdgcn_cvt_pk_fp8_f32(v.z * inv, v.w * inv, p, true);
        ((int*)(xn + (long long)row * IN_DIM))[t] = p;
    }
}

// ---------------------------------------------------------------------------
// Per-row top-K mask in place on fp8 hidden.
// 8-copy bank-spread LDS histogram, wave-0 shuffle suffix-scan, mask from
// registers. Keeps all values >= T (tie surplus contributes ~1e-4 << 0.1).
// ---------------------------------------------------------------------------
__global__ __launch_bounds__(256)
void topk_mask8(unsigned int* __restrict__ H)
{
    __shared__ unsigned int hist8[256 * 8];
    __shared__ unsigned int sT;
    const int t = threadIdx.x;
    unsigned int* row = H + (size_t)blockIdx.x * (HIDDEN / 4);

    #pragma unroll
    for (int i = 0; i < 8; ++i) hist8[i * 256 + t] = 0;
    __syncthreads();

    unsigned int rw[8];
    const int cp = t & 7;
    #pragma unroll
    for (int i = 0; i < 8; ++i) {
        rw[i] = row[i * 256 + t];
        #pragma unroll
        for (int e = 0; e < 4; ++e) {
            const unsigned int b = (rw[i] >> (8 * e)) & 0xFFu;
            const unsigned int k = b ^ ((b & 0x80u) ? 0xFFu : 0x80u);
            atomicAdd(&hist8[k * 8 + cp], 1u);
        }
    }
    __syncthreads();

    unsigned int cnt = 0;
    #pragma unroll
    for (int c = 0; c < 8; ++c) cnt += hist8[t * 8 + c];
    __syncthreads();
    hist8[t] = cnt;
    __syncthreads();

    if (t < 64) {
        const uint4 c4 = *(const uint4*)&hist8[4 * t];
        const unsigned s3 = c4.w;
        const unsigned s2 = c4.z + s3;
        const unsigned s1 = c4.y + s2;
        const unsigned s0 = c4.x + s1;
        unsigned inc = s0;
        #pragma unroll
        for (int off = 1; off < 64; off <<= 1) {
            unsigned o = __shfl_down(inc, off);
            if (t + off >= 64) o = 0;
            inc += o;
        }
        const unsigned carry = inc - s0;
        const unsigned a0 = s0 + carry, a1 = s1 + carry;
        const unsigned a2 = s2 + carry, a3 = s3 + carry;
        if (a0 >= KEEP && a1 < KEEP)    sT = 4u * t + 0u;
        if (a1 >= KEEP && a2 < KEEP)    sT = 4u * t + 1u;
        if (a2 >= KEEP && a3 < KEEP)    sT = 4u * t + 2u;
        if (a3 >= KEEP && carry < KEEP) sT = 4u * t + 3u;
    }
    __syncthreads();
    const unsigned int T = sT;

    #pragma unroll
    for (int i = 0; i < 8; ++i) {
        const unsigned int kw = rw[i];
        unsigned int ow = 0;
        #pragma unroll
        for (int e = 0; e < 4; ++e) {
            const unsigned int b = (kw >> (8 * e)) & 0xFFu;
            const unsigned int k = b ^ ((b & 0x80u) ? 0xFFu : 0x80u);
            if (k >= T) ow |= b << (8 * e);
        }
        row[i * 256 + t] = ow;
    }
}

// ---------------------------------------------------------------------------
extern "C" void kernel_launch(void* const* d_in, const int* in_sizes, int n_in,
                              void* d_out, int out_size, void* d_ws, size_t ws_size,
                              hipStream_t stream)
{
    const float* x    = (const float*)d_in[0];   // [4096,1024]
    const float* Wenc = (const float*)d_in[1];   // [8192,1024]
    const float* Wdec = (const float*)d_in[2];   // [1024,8192]
    const float* gate = (const float*)d_in[3];   // [1024]
    float* out = (float*)d_out;

    char* ws = (char*)d_ws;
    unsigned char* xn    = (unsigned char*)(ws);                        //  4 MB
    unsigned char* WencB = (unsigned char*)(ws + (size_t)( 4 << 20));   //  8 MB
    unsigned char* WdecB = (unsigned char*)(ws + (size_t)(12 << 20));   //  8 MB
    unsigned char* Hbuf  = (unsigned char*)(ws + (size_t)(20 << 20));   // 32 MB
    __bf16*        Part  = (__bf16*)       (ws + (size_t)(52 << 20));   // 16 MB

    constexpr int N4 = HIDDEN * IN_DIM / 4;
    prep<<<2 * N4 / 256 + B_ROWS, 256, 0, stream>>>(Wenc, Wdec, x, WencB, WdecB, xn);

    // hidden[4096,8192] = xn @ Wenc^T  (fp8 out)
    gemm_nt_fp8<128, 128, 2, 2, 0><<<dim3(HIDDEN / 128, B_ROWS / 128, 1), 256, 0, stream>>>(
        xn, IN_DIM, WencB, IN_DIM, (void*)Hbuf, B_ROWS, HIDDEN, IN_DIM);

    topk_mask8<<<B_ROWS, 256, 0, stream>>>((unsigned int*)Hbuf);

    // partials[z][4096,1024] = act_z @ Wdec_z^T  (bf16 out, split-K=2)
    gemm_nt_fp8<128, 64, 2, 2, 1><<<dim3(IN_DIM / 64, B_ROWS / 128, 2), 256, 0, stream>>>(
        Hbuf, HIDDEN, WdecB, HIDDEN, (void*)Part, B_ROWS, IN_DIM, HIDDEN / 2);

    reduce_out<<<B_ROWS * IN_DIM / 4 / 256, 256, 0, stream>>>(Part, x, gate, out);
}